// Round 1
// baseline (2136.316 us; speedup 1.0000x reference)
//
#include <hip/hip_runtime.h>
#include <math.h>

#define DIM 1024
#define SEQ 2048
#define BATCH 4
#define ROWS (BATCH*SEQ)        // 8192
#define CHUNKS 16
#define CLEN (SEQ/CHUNKS)       // 128
#define LN_EPS 1e-5f

// ---------------------------------------------------------------------------
// GEMM (NT): C[m,n] = sum_k A[m,k] * W[n,k] + bias[n]  (+ resid[m,n])
// fp32 correctness-first version. 64x64 tile, BK=32, 256 thr, 4x4 per thread.
// ---------------------------------------------------------------------------
template<bool ADD_RESID>
__global__ __launch_bounds__(256)
void gemm_nt(const float* __restrict__ A, const float* __restrict__ W,
             const float* __restrict__ bias, const float* __restrict__ resid,
             float* __restrict__ C, int M, int N, int K)
{
    __shared__ float As[64][33];   // pad 33: compute reads are <=2-way (free)
    __shared__ float Ws[64][33];
    const int bm = blockIdx.x * 64;
    const int bn = blockIdx.y * 64;
    const int t  = threadIdx.x;
    const int tx = t & 15;         // output col group
    const int ty = t >> 4;         // output row group
    const int lrow = t >> 2;       // 0..63 load row
    const int lc4  = t & 3;        // 0..3 float4 slot
    float acc[4][4] = {};

    for (int k0 = 0; k0 < K; k0 += 32) {
        const float4* Ar = (const float4*)(A + (size_t)(bm + lrow) * K + k0);
        const float4* Wr = (const float4*)(W + (size_t)(bn + lrow) * K + k0);
        float4 a0 = Ar[lc4];
        float4 a1 = Ar[lc4 + 4];
        float4 w0 = Wr[lc4];
        float4 w1 = Wr[lc4 + 4];
        // scalar LDS stores (pad 33 breaks b128 alignment; writes are cheap)
        int c0 = lc4 * 4;
        As[lrow][c0+0]=a0.x; As[lrow][c0+1]=a0.y; As[lrow][c0+2]=a0.z; As[lrow][c0+3]=a0.w;
        As[lrow][16+c0+0]=a1.x; As[lrow][16+c0+1]=a1.y; As[lrow][16+c0+2]=a1.z; As[lrow][16+c0+3]=a1.w;
        Ws[lrow][c0+0]=w0.x; Ws[lrow][c0+1]=w0.y; Ws[lrow][c0+2]=w0.z; Ws[lrow][c0+3]=w0.w;
        Ws[lrow][16+c0+0]=w1.x; Ws[lrow][16+c0+1]=w1.y; Ws[lrow][16+c0+2]=w1.z; Ws[lrow][16+c0+3]=w1.w;
        __syncthreads();
        #pragma unroll
        for (int kk = 0; kk < 32; ++kk) {
            float a[4], w[4];
            #pragma unroll
            for (int i = 0; i < 4; ++i) a[i] = As[ty*4+i][kk];
            #pragma unroll
            for (int j = 0; j < 4; ++j) w[j] = Ws[tx*4+j][kk];
            #pragma unroll
            for (int i = 0; i < 4; ++i)
                #pragma unroll
                for (int j = 0; j < 4; ++j)
                    acc[i][j] += a[i] * w[j];
        }
        __syncthreads();
    }

    #pragma unroll
    for (int i = 0; i < 4; ++i) {
        int row = bm + ty*4 + i;
        #pragma unroll
        for (int j = 0; j < 4; ++j) {
            int col = bn + tx*4 + j;
            float v = acc[i][j] + bias[col];
            if (ADD_RESID) v += resid[(size_t)row * N + col];
            C[(size_t)row * N + col] = v;
        }
    }
}

// ---------------------------------------------------------------------------
// Phase elementwise (in place):
//   a   = value * cos(bp + kplin*ms)   (over value buffer)
//   bi  = value * sin(bp + kplin*ms)   (over kplin buffer)
//   qp  = bp + qplin*ms                (over qplin buffer)
// ---------------------------------------------------------------------------
__global__ __launch_bounds__(256)
void phase_elem(float* __restrict__ val_a, float* __restrict__ kplin_bi,
                float* __restrict__ qplin_qp, const float* __restrict__ bp,
                const float* __restrict__ ms_p)
{
    size_t i = (size_t)blockIdx.x * blockDim.x + threadIdx.x;
    const float ms = ms_p[0];
    int sd = (int)(i & ((size_t)SEQ * DIM - 1));   // SEQ*DIM is 2^21
    float b  = bp[sd];
    float v  = val_a[i];
    float kp = b + kplin_bi[i] * ms;
    float qp = b + qplin_qp[i] * ms;
    float sk, ck;
    sincosf(kp, &sk, &ck);
    val_a[i]    = v * ck;
    kplin_bi[i] = v * sk;
    qplin_qp[i] = qp;
}

// ---------------------------------------------------------------------------
// Scan pass 1: per (b, chunk, d) partial sums of a and bi over CLEN steps.
// ---------------------------------------------------------------------------
__global__ __launch_bounds__(256)
void scan_pass1(const float* __restrict__ a, const float* __restrict__ bi,
                float* __restrict__ sumr, float* __restrict__ sumi)
{
    int gid = blockIdx.x * blockDim.x + threadIdx.x;   // BATCH*CHUNKS*DIM
    int d = gid & (DIM - 1);
    int c = (gid >> 10) & (CHUNKS - 1);
    int b = gid >> 14;
    size_t base = ((size_t)(b * SEQ + c * CLEN)) * DIM + d;
    float sr = 0.f, si = 0.f;
    for (int s = 0; s < CLEN; ++s) {
        sr += a[base + (size_t)s * DIM];
        si += bi[base + (size_t)s * DIM];
    }
    sumr[gid] = sr;
    sumi[gid] = si;
}

// ---------------------------------------------------------------------------
// Scan pass 2: exclusive prefix over the CHUNKS chunk-sums per (b,d), in place
// ---------------------------------------------------------------------------
__global__ __launch_bounds__(256)
void scan_pass2(float* __restrict__ sumr, float* __restrict__ sumi)
{
    int gid = blockIdx.x * blockDim.x + threadIdx.x;   // BATCH*DIM
    int d = gid & (DIM - 1);
    int b = gid >> 10;
    float rr = 0.f, ri = 0.f;
    for (int c = 0; c < CHUNKS; ++c) {
        int idx = (b * CHUNKS + c) * DIM + d;
        float tr = sumr[idx], ti = sumi[idx];
        sumr[idx] = rr;  sumi[idx] = ri;
        rr += tr;  ri += ti;
    }
}

// ---------------------------------------------------------------------------
// Scan pass 3: running inclusive sums + retrieved, written in place over qp.
//   retr = (mem_r*cos(qp) + mem_i*sin(qp)) / sqrt(DIM)
// ---------------------------------------------------------------------------
__global__ __launch_bounds__(256)
void scan_pass3(const float* __restrict__ a, const float* __restrict__ bi,
                float* __restrict__ qp_retr,
                const float* __restrict__ sumr, const float* __restrict__ sumi)
{
    int gid = blockIdx.x * blockDim.x + threadIdx.x;   // BATCH*CHUNKS*DIM
    int d = gid & (DIM - 1);
    int c = (gid >> 10) & (CHUNKS - 1);
    int b = gid >> 14;
    size_t base = ((size_t)(b * SEQ + c * CLEN)) * DIM + d;
    float rr = sumr[gid], ri = sumi[gid];
    const float inv_sqrt_dim = 0.03125f;   // 1/sqrt(1024)
    for (int s = 0; s < CLEN; ++s) {
        size_t idx = base + (size_t)s * DIM;
        rr += a[idx];
        ri += bi[idx];
        float q = qp_retr[idx];
        float sq, cq;
        sincosf(q, &sq, &cq);
        qp_retr[idx] = (rr * cq + ri * sq) * inv_sqrt_dim;
    }
}

// ---------------------------------------------------------------------------
// LayerNorm per row (population variance), 256 thr/row, float4 per thread.
// ---------------------------------------------------------------------------
__global__ __launch_bounds__(256)
void layernorm_k(const float* __restrict__ in, const float* __restrict__ g,
                 const float* __restrict__ beta, float* __restrict__ out)
{
    int row = blockIdx.x;
    int t = threadIdx.x;
    const float4 v = ((const float4*)(in + (size_t)row * DIM))[t];
    float s  = v.x + v.y + v.z + v.w;
    float ss = v.x*v.x + v.y*v.y + v.z*v.z + v.w*v.w;
    #pragma unroll
    for (int o = 32; o >= 1; o >>= 1) {
        s  += __shfl_down(s, o);
        ss += __shfl_down(ss, o);
    }
    __shared__ float red[8];
    int wid = t >> 6, lane = t & 63;
    if (lane == 0) { red[wid] = s; red[wid + 4] = ss; }
    __syncthreads();
    if (t == 0) {
        float S  = red[0] + red[1] + red[2] + red[3];
        float SS = red[4] + red[5] + red[6] + red[7];
        red[0] = S; red[4] = SS;
    }
    __syncthreads();
    float mu  = red[0] * (1.0f / DIM);
    float var = red[4] * (1.0f / DIM) - mu * mu;
    float rstd = rsqrtf(var + LN_EPS);
    float4 gv = ((const float4*)g)[t];
    float4 bv = ((const float4*)beta)[t];
    float4 o;
    o.x = (v.x - mu) * rstd * gv.x + bv.x;
    o.y = (v.y - mu) * rstd * gv.y + bv.y;
    o.z = (v.z - mu) * rstd * gv.z + bv.z;
    o.w = (v.w - mu) * rstd * gv.w + bv.w;
    ((float4*)(out + (size_t)row * DIM))[t] = o;
}

// ---------------------------------------------------------------------------
extern "C" void kernel_launch(void* const* d_in, const int* in_sizes, int n_in,
                              void* d_out, int out_size, void* d_ws, size_t ws_size,
                              hipStream_t stream)
{
    const float* x   = (const float*)d_in[0];
    const float* bp  = (const float*)d_in[1];
    const float* Wk  = (const float*)d_in[2];
    const float* bk  = (const float*)d_in[3];
    const float* Wv  = (const float*)d_in[4];
    const float* bv  = (const float*)d_in[5];
    const float* Wq  = (const float*)d_in[6];
    const float* bq  = (const float*)d_in[7];
    const float* Wkm = (const float*)d_in[8];
    const float* bkm = (const float*)d_in[9];
    const float* Wqm = (const float*)d_in[10];
    const float* bqm = (const float*)d_in[11];
    const float* ms  = (const float*)d_in[12];
    const float* lng = (const float*)d_in[13];
    const float* lnb = (const float*)d_in[14];
    const float* Wo  = (const float*)d_in[15];
    const float* bo  = (const float*)d_in[16];
    float* out = (float*)d_out;

    const size_t NE = (size_t)ROWS * DIM;            // 8.4M floats
    float* buf0 = (float*)d_ws;                      // key -> query -> value -> a -> normed
    float* buf1 = buf0 + NE;                         // kplin -> bi
    float* buf2 = buf1 + NE;                         // qplin -> qp -> retrieved
    float* sumr = buf2 + NE;                         // BATCH*CHUNKS*DIM
    float* sumi = sumr + (size_t)BATCH * CHUNKS * DIM;

    dim3 gg(ROWS / 64, DIM / 64);

    // key = x @ Wk^T + bk
    gemm_nt<false><<<gg, 256, 0, stream>>>(x,    Wk,  bk,  nullptr, buf0, ROWS, DIM, DIM);
    // kplin = key @ Wkm^T + bkm
    gemm_nt<false><<<gg, 256, 0, stream>>>(buf0, Wkm, bkm, nullptr, buf1, ROWS, DIM, DIM);
    // query = x @ Wq^T + bq   (overwrites key)
    gemm_nt<false><<<gg, 256, 0, stream>>>(x,    Wq,  bq,  nullptr, buf0, ROWS, DIM, DIM);
    // qplin = query @ Wqm^T + bqm
    gemm_nt<false><<<gg, 256, 0, stream>>>(buf0, Wqm, bqm, nullptr, buf2, ROWS, DIM, DIM);
    // value = x @ Wv^T + bv   (overwrites query)
    gemm_nt<false><<<gg, 256, 0, stream>>>(x,    Wv,  bv,  nullptr, buf0, ROWS, DIM, DIM);

    // phases + cos/sin products (all in place)
    phase_elem<<<(int)(NE / 256), 256, 0, stream>>>(buf0, buf1, buf2, bp, ms);

    // chunked inclusive scan + retrieved
    scan_pass1<<<(BATCH * CHUNKS * DIM) / 256, 256, 0, stream>>>(buf0, buf1, sumr, sumi);
    scan_pass2<<<(BATCH * DIM) / 256, 256, 0, stream>>>(sumr, sumi);
    scan_pass3<<<(BATCH * CHUNKS * DIM) / 256, 256, 0, stream>>>(buf0, buf1, buf2, sumr, sumi);

    // layernorm: retrieved(buf2) -> normed(buf0)
    layernorm_k<<<ROWS, 256, 0, stream>>>(buf2, lng, lnb, buf0);

    // out = x + normed @ Wo^T + bo
    gemm_nt<true><<<gg, 256, 0, stream>>>(buf0, Wo, bo, x, out, ROWS, DIM, DIM);
}

// Round 2
// 327.685 us; speedup vs baseline: 6.5194x; 6.5194x over previous
//
#include <hip/hip_runtime.h>
#include <math.h>

#define DIM 1024
#define SEQ 2048
#define BATCH 4
#define ROWS (BATCH*SEQ)        // 8192
#define CHUNKS 16
#define CLEN (SEQ/CHUNKS)       // 128
#define LN_EPS 1e-5f

typedef unsigned short ushort_t;
typedef __attribute__((ext_vector_type(8))) short bf16x8;
typedef __attribute__((ext_vector_type(4))) float f32x4;

// fp32 -> bf16 round-to-nearest-even
__device__ inline ushort_t f2bf(float f) {
    union { float f; unsigned u; } v; v.f = f;
    unsigned r = v.u + 0x7FFFu + ((v.u >> 16) & 1u);
    return (ushort_t)(r >> 16);
}

// ---------------------------------------------------------------------------
// fp32 -> bf16 conversion, 8 elements/thread (count must be multiple of 2048)
// ---------------------------------------------------------------------------
__global__ __launch_bounds__(256)
void f32_to_bf16_k(const float* __restrict__ in, ushort_t* __restrict__ out)
{
    size_t i = ((size_t)blockIdx.x * 256 + threadIdx.x) * 8;
    float4 a = *(const float4*)(in + i);
    float4 b = *(const float4*)(in + i + 4);
    ushort4 lo, hi;
    lo.x = f2bf(a.x); lo.y = f2bf(a.y); lo.z = f2bf(a.z); lo.w = f2bf(a.w);
    hi.x = f2bf(b.x); hi.y = f2bf(b.y); hi.z = f2bf(b.z); hi.w = f2bf(b.w);
    *(ushort4*)(out + i) = lo;
    *(ushort4*)(out + i + 4) = hi;
}

// ---------------------------------------------------------------------------
// bf16 MFMA GEMM (NT): C[m,n] = sum_k A[m,k]*W[n,k] + bias[n] (+resid[m,n])
// m97 structure: 128x128 tile, BK=32, 4 waves (2x2), global_load_lds w=16,
// linear LDS [128][32] bf16, 2 barriers per K-step, 16x16x32 MFMA, 4x4 frags.
// ---------------------------------------------------------------------------
template<bool OUT_BF16, bool ADD_RESID>
__global__ __launch_bounds__(256)
void gemm_bf16_nt(const ushort_t* __restrict__ A, const ushort_t* __restrict__ W,
                  const float* __restrict__ bias, const float* __restrict__ resid,
                  void* __restrict__ Cout, int M, int N, int K)
{
    __shared__ ushort_t As[128 * 32];
    __shared__ ushort_t Bs[128 * 32];
    const int bm = blockIdx.x * 128;
    const int bn = blockIdx.y * 128;
    const int t = threadIdx.x;
    const int lane = t & 63;
    const int w = t >> 6;            // wave 0..3
    const int wr = w >> 1;           // wave row 0..1
    const int wc = w & 1;            // wave col 0..1

    f32x4 acc[4][4] = {};

    const int fr = lane & 15;        // fragment row/col within 16
    const int kc = (lane >> 4) * 8;  // k offset within 32

    for (int k0 = 0; k0 < K; k0 += 32) {
        // stage 128x32 A-tile + 128x32 B-tile (8KB each) via async copy.
        // chunk c (16B): row=c>>2, col8=(c&3)*8; LDS linear offset c*16B.
        #pragma unroll
        for (int i = 0; i < 2; ++i) {
            int c = t + i * 256;
            int row = c >> 2;
            int col = (c & 3) * 8;
            const ushort_t* ga = A + (size_t)(bm + row) * K + k0 + col;
            __builtin_amdgcn_global_load_lds(
                (const __attribute__((address_space(1))) void*)ga,
                (__attribute__((address_space(3))) void*)(As + (size_t)c * 8),
                16, 0, 0);
            const ushort_t* gb = W + (size_t)(bn + row) * K + k0 + col;
            __builtin_amdgcn_global_load_lds(
                (const __attribute__((address_space(1))) void*)gb,
                (__attribute__((address_space(3))) void*)(Bs + (size_t)c * 8),
                16, 0, 0);
        }
        __syncthreads();   // drains vmcnt: tiles ready

        bf16x8 af[4], bw[4];
        #pragma unroll
        for (int m2 = 0; m2 < 4; ++m2)
            af[m2] = *(const bf16x8*)(As + (wr * 64 + m2 * 16 + fr) * 32 + kc);
        #pragma unroll
        for (int n2 = 0; n2 < 4; ++n2)
            bw[n2] = *(const bf16x8*)(Bs + (wc * 64 + n2 * 16 + fr) * 32 + kc);
        #pragma unroll
        for (int m2 = 0; m2 < 4; ++m2)
            #pragma unroll
            for (int n2 = 0; n2 < 4; ++n2)
                acc[m2][n2] = __builtin_amdgcn_mfma_f32_16x16x32_bf16(
                    af[m2], bw[n2], acc[m2][n2], 0, 0, 0);
        __syncthreads();   // all reads done before next stage overwrites
    }

    // epilogue: C/D layout col=lane&15, row=(lane>>4)*4+reg
    const int fc = lane & 15;
    const int r0 = (lane >> 4) * 4;
    #pragma unroll
    for (int m2 = 0; m2 < 4; ++m2) {
        #pragma unroll
        for (int n2 = 0; n2 < 4; ++n2) {
            int col = bn + wc * 64 + n2 * 16 + fc;
            float bv = bias[col];
            #pragma unroll
            for (int r = 0; r < 4; ++r) {
                int row = bm + wr * 64 + m2 * 16 + r0 + r;
                float v = acc[m2][n2][r] + bv;
                if (ADD_RESID) v += resid[(size_t)row * N + col];
                if (OUT_BF16)
                    ((ushort_t*)Cout)[(size_t)row * N + col] = f2bf(v);
                else
                    ((float*)Cout)[(size_t)row * N + col] = v;
            }
        }
    }
}

// ---------------------------------------------------------------------------
// Phase elementwise (in place):
//   a  = value * cos(bp + kplin*ms)   (over value buffer)
//   bi = value * sin(bp + kplin*ms)   (over kplin buffer)
//   qp = bp + qplin*ms                (over qplin buffer)
// ---------------------------------------------------------------------------
__global__ __launch_bounds__(256)
void phase_elem(float* __restrict__ val_a, float* __restrict__ kplin_bi,
                float* __restrict__ qplin_qp, const float* __restrict__ bp,
                const float* __restrict__ ms_p)
{
    size_t i = (size_t)blockIdx.x * blockDim.x + threadIdx.x;
    const float ms = ms_p[0];
    int sd = (int)(i & ((size_t)SEQ * DIM - 1));   // SEQ*DIM is 2^21
    float b  = bp[sd];
    float v  = val_a[i];
    float kp = b + kplin_bi[i] * ms;
    float qp = b + qplin_qp[i] * ms;
    float sk, ck;
    sincosf(kp, &sk, &ck);
    val_a[i]    = v * ck;
    kplin_bi[i] = v * sk;
    qplin_qp[i] = qp;
}

// ---------------------------------------------------------------------------
// Scan pass 1: per (b, chunk, d) partial sums of a and bi over CLEN steps.
// ---------------------------------------------------------------------------
__global__ __launch_bounds__(256)
void scan_pass1(const float* __restrict__ a, const float* __restrict__ bi,
                float* __restrict__ sumr, float* __restrict__ sumi)
{
    int gid = blockIdx.x * blockDim.x + threadIdx.x;   // BATCH*CHUNKS*DIM
    int d = gid & (DIM - 1);
    int c = (gid >> 10) & (CHUNKS - 1);
    int b = gid >> 14;
    size_t base = ((size_t)(b * SEQ + c * CLEN)) * DIM + d;
    float sr = 0.f, si = 0.f;
    for (int s = 0; s < CLEN; ++s) {
        sr += a[base + (size_t)s * DIM];
        si += bi[base + (size_t)s * DIM];
    }
    sumr[gid] = sr;
    sumi[gid] = si;
}

// ---------------------------------------------------------------------------
// Scan pass 2: exclusive prefix over the CHUNKS chunk-sums per (b,d), in place
// ---------------------------------------------------------------------------
__global__ __launch_bounds__(256)
void scan_pass2(float* __restrict__ sumr, float* __restrict__ sumi)
{
    int gid = blockIdx.x * blockDim.x + threadIdx.x;   // BATCH*DIM
    int d = gid & (DIM - 1);
    int b = gid >> 10;
    float rr = 0.f, ri = 0.f;
    for (int c = 0; c < CHUNKS; ++c) {
        int idx = (b * CHUNKS + c) * DIM + d;
        float tr = sumr[idx], ti = sumi[idx];
        sumr[idx] = rr;  sumi[idx] = ri;
        rr += tr;  ri += ti;
    }
}

// ---------------------------------------------------------------------------
// Scan pass 3: running inclusive sums + retrieved, written in place over qp.
//   retr = (mem_r*cos(qp) + mem_i*sin(qp)) / sqrt(DIM)
// ---------------------------------------------------------------------------
__global__ __launch_bounds__(256)
void scan_pass3(const float* __restrict__ a, const float* __restrict__ bi,
                float* __restrict__ qp_retr,
                const float* __restrict__ sumr, const float* __restrict__ sumi)
{
    int gid = blockIdx.x * blockDim.x + threadIdx.x;   // BATCH*CHUNKS*DIM
    int d = gid & (DIM - 1);
    int c = (gid >> 10) & (CHUNKS - 1);
    int b = gid >> 14;
    size_t base = ((size_t)(b * SEQ + c * CLEN)) * DIM + d;
    float rr = sumr[gid], ri = sumi[gid];
    const float inv_sqrt_dim = 0.03125f;   // 1/sqrt(1024)
    for (int s = 0; s < CLEN; ++s) {
        size_t idx = base + (size_t)s * DIM;
        rr += a[idx];
        ri += bi[idx];
        float q = qp_retr[idx];
        float sq, cq;
        sincosf(q, &sq, &cq);
        qp_retr[idx] = (rr * cq + ri * sq) * inv_sqrt_dim;
    }
}

// ---------------------------------------------------------------------------
// LayerNorm per row (population variance) -> bf16 output for final GEMM.
// ---------------------------------------------------------------------------
__global__ __launch_bounds__(256)
void layernorm_bf16(const float* __restrict__ in, const float* __restrict__ g,
                    const float* __restrict__ beta, ushort_t* __restrict__ out)
{
    int row = blockIdx.x;
    int t = threadIdx.x;
    const float4 v = ((const float4*)(in + (size_t)row * DIM))[t];
    float s  = v.x + v.y + v.z + v.w;
    float ss = v.x*v.x + v.y*v.y + v.z*v.z + v.w*v.w;
    #pragma unroll
    for (int o = 32; o >= 1; o >>= 1) {
        s  += __shfl_down(s, o);
        ss += __shfl_down(ss, o);
    }
    __shared__ float red[8];
    int wid = t >> 6, lane = t & 63;
    if (lane == 0) { red[wid] = s; red[wid + 4] = ss; }
    __syncthreads();
    if (t == 0) {
        float S  = red[0] + red[1] + red[2] + red[3];
        float SS = red[4] + red[5] + red[6] + red[7];
        red[0] = S; red[4] = SS;
    }
    __syncthreads();
    float mu  = red[0] * (1.0f / DIM);
    float var = red[4] * (1.0f / DIM) - mu * mu;
    float rstd = rsqrtf(var + LN_EPS);
    float4 gv = ((const float4*)g)[t];
    float4 bv = ((const float4*)beta)[t];
    ushort4 o;
    o.x = f2bf((v.x - mu) * rstd * gv.x + bv.x);
    o.y = f2bf((v.y - mu) * rstd * gv.y + bv.y);
    o.z = f2bf((v.z - mu) * rstd * gv.z + bv.z);
    o.w = f2bf((v.w - mu) * rstd * gv.w + bv.w);
    ((ushort4*)(out + (size_t)row * DIM))[t] = o;
}

// ---------------------------------------------------------------------------
extern "C" void kernel_launch(void* const* d_in, const int* in_sizes, int n_in,
                              void* d_out, int out_size, void* d_ws, size_t ws_size,
                              hipStream_t stream)
{
    const float* x   = (const float*)d_in[0];
    const float* bp  = (const float*)d_in[1];
    const float* Wk  = (const float*)d_in[2];
    const float* bk  = (const float*)d_in[3];
    const float* Wv  = (const float*)d_in[4];
    const float* bv  = (const float*)d_in[5];
    const float* Wq  = (const float*)d_in[6];
    const float* bq  = (const float*)d_in[7];
    const float* Wkm = (const float*)d_in[8];
    const float* bkm = (const float*)d_in[9];
    const float* Wqm = (const float*)d_in[10];
    const float* bqm = (const float*)d_in[11];
    const float* ms  = (const float*)d_in[12];
    const float* lng = (const float*)d_in[13];
    const float* lnb = (const float*)d_in[14];
    const float* Wo  = (const float*)d_in[15];
    const float* bo  = (const float*)d_in[16];
    float* out = (float*)d_out;

    const size_t NE = (size_t)ROWS * DIM;            // 8.4M
    const size_t WN = (size_t)DIM * DIM;             // 1M

    float* buf0 = (float*)d_ws;                      // value/a (fp32); front reused as bf16 act
    float* buf1 = buf0 + NE;                         // kplin/bi
    float* buf2 = buf1 + NE;                         // qplin/qp/retrieved
    ushort_t* xbf  = (ushort_t*)(buf2 + NE);         // bf16 x
    ushort_t* wbf  = xbf + NE;                       // 6 bf16 weights
    float* sumr = (float*)(wbf + 6 * WN);
    float* sumi = sumr + (size_t)BATCH * CHUNKS * DIM;
    ushort_t* actbf = (ushort_t*)buf0;               // key_bf / query_bf / normed_bf

    ushort_t* wk_b  = wbf;
    ushort_t* wkm_b = wbf + WN;
    ushort_t* wq_b  = wbf + 2 * WN;
    ushort_t* wqm_b = wbf + 3 * WN;
    ushort_t* wv_b  = wbf + 4 * WN;
    ushort_t* wo_b  = wbf + 5 * WN;

    // --- convert inputs to bf16 ---
    f32_to_bf16_k<<<(int)(NE / 2048), 256, 0, stream>>>(x, xbf);
    f32_to_bf16_k<<<(int)(WN / 2048), 256, 0, stream>>>(Wk,  wk_b);
    f32_to_bf16_k<<<(int)(WN / 2048), 256, 0, stream>>>(Wkm, wkm_b);
    f32_to_bf16_k<<<(int)(WN / 2048), 256, 0, stream>>>(Wq,  wq_b);
    f32_to_bf16_k<<<(int)(WN / 2048), 256, 0, stream>>>(Wqm, wqm_b);
    f32_to_bf16_k<<<(int)(WN / 2048), 256, 0, stream>>>(Wv,  wv_b);
    f32_to_bf16_k<<<(int)(WN / 2048), 256, 0, stream>>>(Wo,  wo_b);

    dim3 gg(ROWS / 128, DIM / 128);   // 64 x 8

    // key_bf = bf16(x @ Wk^T + bk)
    gemm_bf16_nt<true,  false><<<gg, 256, 0, stream>>>(xbf,   wk_b,  bk,  nullptr, actbf, ROWS, DIM, DIM);
    // kplin = fp32(key_bf @ Wkm^T + bkm)
    gemm_bf16_nt<false, false><<<gg, 256, 0, stream>>>(actbf, wkm_b, bkm, nullptr, buf1,  ROWS, DIM, DIM);
    // query_bf = bf16(x @ Wq^T + bq)
    gemm_bf16_nt<true,  false><<<gg, 256, 0, stream>>>(xbf,   wq_b,  bq,  nullptr, actbf, ROWS, DIM, DIM);
    // qplin = fp32(query_bf @ Wqm^T + bqm)
    gemm_bf16_nt<false, false><<<gg, 256, 0, stream>>>(actbf, wqm_b, bqm, nullptr, buf2,  ROWS, DIM, DIM);
    // value = fp32(x @ Wv^T + bv)   (overwrites actbf region; query consumed)
    gemm_bf16_nt<false, false><<<gg, 256, 0, stream>>>(xbf,   wv_b,  bv,  nullptr, buf0,  ROWS, DIM, DIM);

    // phases + cos/sin products (in place)
    phase_elem<<<(int)(NE / 256), 256, 0, stream>>>(buf0, buf1, buf2, bp, ms);

    // chunked inclusive scan + retrieved
    scan_pass1<<<(BATCH * CHUNKS * DIM) / 256, 256, 0, stream>>>(buf0, buf1, sumr, sumi);
    scan_pass2<<<(BATCH * DIM) / 256, 256, 0, stream>>>(sumr, sumi);
    scan_pass3<<<(BATCH * CHUNKS * DIM) / 256, 256, 0, stream>>>(buf0, buf1, buf2, sumr, sumi);

    // layernorm: retrieved(buf2) -> normed_bf (buf0 region; 'a' is dead)
    layernorm_bf16<<<ROWS, 256, 0, stream>>>(buf2, lng, lnb, actbf);

    // out = x + normed_bf @ Wo^T + bo
    gemm_bf16_nt<false, true><<<gg, 256, 0, stream>>>(actbf, wo_b, bo, x, out, ROWS, DIM, DIM);
}